// Round 8
// baseline (1112.226 us; speedup 1.0000x reference)
//
#include <hip/hip_runtime.h>

// ---------------------------------------------------------------------------
// CommNet round 15 RESUBMIT (R15 bench was an infra failure: container died
// twice, no measurement taken; kernel identical to last round).
//  Theory under test: conv0 pipe REBALANCE (4 LDS + 2 global A-reads).
//  R14 counters: conv0 309us, MfmaUtil 39.8, VALU 36.0 -> the R13/14 staging
//  moved ALL A-traffic onto the LDS pipe: 6KB/step LDS (~54cy) vs 2KB/step
//  L1 (~16cy); LDS pipe now binds. Optimal split ~4KB/4KB:
//   - A dy=0 (3 xt) + dy=1 xt=0 from LDS; A dy=1 xt=1,2 from GLOBAL (L1/L2
//     hits: same 18KB footprint the block staged; y-stride 192 els in both
//     address spaces so the +192 dy immediate is shared)
//   - per-lane int2 delta table Dtx[19][64] (x=LDS, y=global): 1 coalesced
//     8B load/step replaces int4 + 3 cndmask (VALU trim)
//  conv1/conv2 untouched (one variable). Tripwire: WRITE_SIZE 46MB = no spill.
// Layouts (HW-verified): A[m=lane&15][k=q*8+j], B[n=lane&15][k=q*8+j],
//  D col=lane&15, row=q*4+reg.
// ---------------------------------------------------------------------------

typedef __attribute__((ext_vector_type(8)))  _Float16 f16x8;
typedef __attribute__((ext_vector_type(8), aligned(8))) _Float16 f16x8u; // 8B-aligned 16B access
typedef __attribute__((ext_vector_type(4)))  float f32x4;

__device__ __forceinline__ ushort f2h(float f) {
    union { _Float16 h; ushort u; } v;
    v.h = (_Float16)f;                       // v_cvt_f16_f32, RNE
    return v.u;
}
__device__ __forceinline__ float h2f(ushort h) {
    union { ushort u; _Float16 h; } v; v.u = h;
    return (float)v.h;
}

#define MFMA16(A, B, C) __builtin_amdgcn_mfma_f32_16x16x32_f16(A, B, C, 0, 0, 0)

// ---- prep: x [80][4][45^3] fp32 -> hi0 NDHWC padded [80][47][47][48][4] f16
// Covers the FULL padded volume (halos written as zeros -> no memset).
__global__ void pad_input_kernel(const float* __restrict__ x,
                                 ushort* __restrict__ hi)
{
    int t = blockIdx.x * 256 + threadIdx.x;
    const int TOT = 80 * 47 * 47 * 48;
    if (t >= TOT) return;
    int xo = t % 48, r = t / 48;
    int yo = r % 47; r /= 47;
    int zo = r % 47; int n = r / 47;
    ushort h4[4] = {0, 0, 0, 0};
    if (zo >= 1 && zo <= 45 && yo >= 1 && yo <= 45 && xo >= 1 && xo <= 45) {
        int ib = n * 4 * 91125 + (zo - 1) * 2025 + (yo - 1) * 45 + (xo - 1);
        #pragma unroll
        for (int ic = 0; ic < 4; ++ic)
            h4[ic] = f2h(x[ib + ic * 91125] * (1.f / 255.f));
    }
    *(ushort4*)(hi + t * 4) = *(ushort4*)h4;
}

// ---- pack conv0 weights [32][4][5][5][5] -> Bp0[19 s][2 ot][64 lane][8 j] f16
// k = ((kz*5+ky)*6+kx)*4 + ic  (kx in [0,6), kx==5 zero; K=600, 19 steps = 608)
// Dtx[19][64] int2: per-lane deltas; .x = LDS (kz*8+ky)*192+kx*4,
//                                   .y = global (kz*47+ky)*192+kx*4.
__global__ void pack_w0(const float* __restrict__ w, ushort* __restrict__ Bp,
                        int2* __restrict__ Dtx)
{
    int t = blockIdx.x * 256 + threadIdx.x;
    if (t < 19 * 2 * 64 * 8) {
        int j = t & 7, l = (t >> 3) & 63, ot = (t >> 9) & 1, s = t >> 10;
        int oc = ot * 16 + (l & 15);
        int k = 32 * s + ((l >> 4) << 3) + j;
        float v = 0.f;
        if (k < 600) {
            int ic = k & 3, t6 = k >> 2;
            int kx = t6 % 6, q = t6 / 6, ky = q % 5, kz = q / 5;
            if (kx < 5) v = w[(oc * 4 + ic) * 125 + kz * 25 + ky * 5 + kx];
        }
        Bp[t] = f2h(v);
    }
    if (t < 19 * 64) {
        int s = t >> 6, lane = t & 63, q = (lane >> 4) & 3;
        int k = 32 * s + 8 * q;
        int2 d; d.x = 0; d.y = 0;
        if (k < 600) {
            int t6 = k >> 2;
            int kx = t6 % 6, qq = t6 / 6;
            int kz = qq / 5, ky = qq % 5;
            d.x = (kz * 8 + ky) * 192 + kx * 4;      // LDS els
            d.y = (kz * 47 + ky) * 192 + kx * 4;     // global els
        }
        Dtx[t] = d;
    }
}

// ---- pack conv1 weights [32][32][5][5][5] -> Bp1[126 s][2 ot][64][8] f16
// step s = tap, kz-major (125 real; slot 125 unused)
__global__ void pack_w1(const float* __restrict__ w, ushort* __restrict__ Bp)
{
    int t = blockIdx.x * 256 + threadIdx.x;
    if (t < 126 * 2 * 64 * 8) {
        int j = t & 7, l = (t >> 3) & 63, ot = (t >> 9) & 1, s = t >> 10;
        int oc = ot * 16 + (l & 15);
        int ic = ((l >> 4) << 3) + j;
        Bp[t] = (s < 125) ? f2h(w[(oc * 32 + ic) * 125 + s]) : (ushort)0;
    }
}

// ---- pack conv2 weights [64][32][4][4][4] -> Bp2h/Bp2l[64 s][4 nt][64 l][8 j]
__global__ void pack_w2(const float* __restrict__ w,
                        ushort* __restrict__ Bh, ushort* __restrict__ Bl,
                        int* __restrict__ Dt)
{
    int t = blockIdx.x * 256 + threadIdx.x;
    if (t < 64 * 4 * 64 * 8) {
        int j = t & 7, l = (t >> 3) & 63, nt = (t >> 9) & 3, s = t >> 11;
        int oc = nt * 16 + (l & 15);
        int ic = ((l >> 4) << 3) + j;
        int kz = s >> 4, ky = (s >> 2) & 3, kx = s & 3;
        float v = w[(oc * 32 + ic) * 64 + kz * 16 + ky * 4 + kx];
        ushort h = f2h(v);
        Bh[t] = h;
        Bl[t] = f2h(v - h2f(h));
    }
    if (t < 64) {
        int kz = t >> 4, ky = (t >> 2) & 3, kx = t & 3;
        Dt[t] = ((kz * 11 + ky) * 12 + kx) * 32;                     // x-unit=32
    }
}

// ---- conv0 MFMA: hi0 [80][47][47][48][4] f16 -> hi1 [80][23][23][24][32] f16
// block = (pz, pyg); waves (dz,pyl); dy-merged. A split: 4 LDS reads
// (dy0 x3, dy1 xt0) + 2 global reads (dy1 xt1,2); B global.
__global__ __launch_bounds__(256)
void conv0_mfma(const ushort* __restrict__ hi0,
                const ushort* __restrict__ Bp, const int2* __restrict__ Dtx,
                const float* __restrict__ bias, const float* __restrict__ slope,
                ushort* __restrict__ hi1)
{
    const int n   = blockIdx.z;
    const int pz  = blockIdx.x / 11, pyg = blockIdx.x % 11;
    const int tid = threadIdx.x, lane = tid & 63, w = tid >> 6;
    const int dz  = w >> 1, pyl = w & 1;
    const int l15 = lane & 15, q = lane >> 4;

    __shared__ float pool[2][2][21][32];                 // 10.75 KB
    __shared__ __align__(16) ushort As[6 * 8 * 192];     // 18 KB

    {   // stage A footprint: z [2pz,2pz+6), y [4pyg,4pyg+8), x [0,48)*4ic
        const int base = ((n * 47 + 2 * pz) * 47 + 4 * pyg) * 192;
        for (int u = tid; u < 2304; u += 256) {          // 8B units (4 els)
            int zr = u / 384, rem = u - zr * 384;        // rem = yr*48 + xu
            int src = base + zr * 9024 + rem * 4;        // (zr*47+yr)*192+xu*4
            *(uint2*)(As + u * 4) = *(const uint2*)(hi0 + src);
        }
    }

    const float sl = slope[0];
    const int z0 = 2 * pz + dz, y0 = 4 * pyg + 2 * pyl;  // global dy=0 base
    int lb[3], gb[3];
    #pragma unroll
    for (int xt = 0; xt < 3; ++xt) {
        int x = xt * 16 + l15;
        int xr = x > 41 ? 41 : x;
        lb[xt] = (dz * 8 + 2 * pyl) * 192 + xr * 4;
        gb[xt] = (((n * 47 + z0) * 47 + y0) * 48 + xr) * 4;
    }

    f32x4 acc[2][3][2] = {};                  // [dy][xt][ot]
    const f16x8* Bv = (const f16x8*)Bp;
    f16x8 avd[2][3][2], b0v[2], b1v[2];       // [j][xt][dy]

    auto LOADS = [&](int s, int j) {
        int2 dd = Dtx[s * 64 + lane];
        b0v[j] = Bv[(2 * s) * 64 + lane];
        b1v[j] = Bv[(2 * s + 1) * 64 + lane];
        // LDS: dy=0 all xt, dy=1 xt=0
        const ushort* p0 = As + lb[0] + dd.x;
        avd[j][0][0] = *(const f16x8u*)p0;
        avd[j][0][1] = *(const f16x8u*)(p0 + 192);
        avd[j][1][0] = *(const f16x8u*)(As + lb[1] + dd.x);
        avd[j][2][0] = *(const f16x8u*)(As + lb[2] + dd.x);
        // global: dy=1 xt=1,2 (L1/L2-resident; same +192 y immediate)
        avd[j][1][1] = *(const f16x8u*)(hi0 + gb[1] + dd.y + 192);
        avd[j][2][1] = *(const f16x8u*)(hi0 + gb[2] + dd.y + 192);
    };
    auto COMP = [&](int j) {
        #pragma unroll
        for (int xt = 0; xt < 3; ++xt)
            #pragma unroll
            for (int dy = 0; dy < 2; ++dy) {
                acc[dy][xt][0] = MFMA16(avd[j][xt][dy], b0v[j], acc[dy][xt][0]);
                acc[dy][xt][1] = MFMA16(avd[j][xt][dy], b1v[j], acc[dy][xt][1]);
            }
    };

    __syncthreads();                          // A staged

    LOADS(0, 0); LOADS(1, 1);
    for (int s = 0; s < 16; s += 2) {         // branch-free body
        COMP(0); LOADS(s + 2, 0);
        COMP(1); LOADS(s + 3, 1);             // max s+3 = 17
    }
    COMP(0); LOADS(18, 0);
    COMP(1);
    COMP(0);

    #pragma unroll
    for (int xt = 0; xt < 3; ++xt)
        #pragma unroll
        for (int ot = 0; ot < 2; ++ot) {
            float m0 = fmaxf(acc[0][xt][ot][0], acc[1][xt][ot][0]);
            float m1 = fmaxf(acc[0][xt][ot][1], acc[1][xt][ot][1]);
            float m2 = fmaxf(acc[0][xt][ot][2], acc[1][xt][ot][2]);
            float m3 = fmaxf(acc[0][xt][ot][3], acc[1][xt][ot][3]);
            int pxe = xt * 8 + 2 * q, pxo = pxe + 1;
            if (pxe < 21) pool[dz][pyl][pxe][ot * 16 + l15] = fmaxf(m0, m1);
            if (pxo < 21) pool[dz][pyl][pxo][ot * 16 + l15] = fmaxf(m2, m3);
        }
    __syncthreads();

    for (int t2 = tid; t2 < 1344; t2 += 256) {
        int oc = t2 & 31, r = t2 >> 5;
        int px = r % 21, pyl2 = r / 21;
        int py2 = 2 * pyg + pyl2;
        if (py2 > 20) continue;
        float v = fmaxf(pool[0][pyl2][px][oc], pool[1][pyl2][px][oc]);
        v += bias[oc];
        v = (v >= 0.f) ? v : sl * v;
        int o = (((n * 23 + pz + 1) * 23 + py2 + 1) * 24 + px + 1) * 32 + oc;
        hi1[o] = f2h(v);
    }
}

// ---- conv1 MFMA: hi1 [80][23][23][24][32] f16 -> P2h/P2l f16 NDHWC padded
// A via LDS ring of 3 z-slices (15.4KB each), phased over kz (5 x 25 steps),
// T14 async stage. B from global. M flat = pyl*18+x (4 tiles of 16).
__global__ __launch_bounds__(256)
void conv1_mfma(const ushort* __restrict__ hi1,
                const ushort* __restrict__ Bp,
                const float* __restrict__ bias, const float* __restrict__ slope,
                ushort* __restrict__ P2h, ushort* __restrict__ P2l)
{
    const int n   = blockIdx.z;
    const int pz  = blockIdx.x / 3, pyg = blockIdx.x % 3;
    const int tid = threadIdx.x, lane = tid & 63, w = tid >> 6;
    const int dz = w >> 1, dy = w & 1;
    const int q = lane >> 4, l15 = lane & 15;

    __shared__ float pool[4][27][32];                    // 13.5 KB
    __shared__ __align__(16) ushort As[3 * 7680];        // 45 KB (3 z-slices)

    int lb[4];
    #pragma unroll
    for (int t = 0; t < 4; ++t) {
        int flat = t * 16 + l15;
        if (flat > 53) flat = 53;
        int pyl = flat / 18, x = flat - pyl * 18;
        lb[t] = (2 * pyl + dy) * 768 + x * 32 + q * 8;
    }

    f16x8 stg[4];
    auto STAGE_LOAD = [&](int zoff) {                    // issue early (T14)
        const ushort* src = hi1 + ((n * 23 + 2 * pz + zoff) * 23 + 6 * pyg) * 768;
        #pragma unroll
        for (int r = 0; r < 4; ++r) {
            int u = tid + r * 256;
            if (u < 960) stg[r] = *(const f16x8*)(src + u * 8);
        }
    };
    auto STAGE_WRITE = [&](int zoff) {                   // write late
        int slot = zoff % 3;
        #pragma unroll
        for (int r = 0; r < 4; ++r) {
            int u = tid + r * 256;
            if (u < 960) *(f16x8*)(As + slot * 7680 + u * 8) = stg[r];
        }
    };

    f32x4 acc[4][2] = {};
    const f16x8* Bv = (const f16x8*)Bp;
    f16x8 ahv[2][4], b0v[2], b1v[2];

    // prologue: slices 0,1
    STAGE_LOAD(0); STAGE_WRITE(0);
    STAGE_LOAD(1); STAGE_WRITE(1);
    __syncthreads();

    for (int kz = 0; kz < 5; ++kz) {
        if (kz < 4) STAGE_LOAD(kz + 2);
        const int slotbase = ((dz + kz) % 3) * 7680;
        const int sg0 = kz * 25;

        auto LOADS = [&](int s, int j) {                 // s in [0,25)
            int delta = (s / 5) * 768 + (s % 5) * 32;
            int sg = sg0 + s;
            b0v[j] = Bv[(2 * sg) * 64 + lane];
            b1v[j] = Bv[(2 * sg + 1) * 64 + lane];
            #pragma unroll
            for (int t = 0; t < 4; ++t)
                ahv[j][t] = *(const f16x8u*)(As + slotbase + lb[t] + delta);
        };
        auto COMP = [&](int j) {
            #pragma unroll
            for (int t = 0; t < 4; ++t) {
                acc[t][0] = MFMA16(ahv[j][t], b0v[j], acc[t][0]);
                acc[t][1] = MFMA16(ahv[j][t], b1v[j], acc[t][1]);
            }
        };

        LOADS(0, 0); LOADS(1, 1);
        for (int s = 0; s < 24; s += 2) {
            COMP(0); LOADS(s + 2 > 24 ? 24 : s + 2, 0);
            COMP(1); LOADS(s + 3 > 24 ? 24 : s + 3, 1);
        }
        COMP(0);                                         // step 24

        __syncthreads();                                 // phase reads done
        if (kz < 4) STAGE_WRITE(kz + 2);
        __syncthreads();                                 // writes visible
    }

    #pragma unroll
    for (int t = 0; t < 4; ++t) {
        int p0 = t * 8 + q * 2;
        float e0 = fmaxf(acc[t][0][0], acc[t][0][1]);
        float o0 = fmaxf(acc[t][0][2], acc[t][0][3]);
        float e1 = fmaxf(acc[t][1][0], acc[t][1][1]);
        float o1 = fmaxf(acc[t][1][2], acc[t][1][3]);
        if (p0 < 27)     { pool[w][p0][l15] = e0;     pool[w][p0][16 + l15] = e1; }
        if (p0 + 1 < 27) { pool[w][p0 + 1][l15] = o0; pool[w][p0 + 1][16 + l15] = o1; }
    }
    __syncthreads();

    for (int t2 = tid; t2 < 864; t2 += 256) {
        int oc = t2 & 31, pr = t2 >> 5;          // pr = pyl*9 + px
        int pyl = pr / 9, px = pr % 9;
        float v = fmaxf(fmaxf(pool[0][pr][oc], pool[1][pr][oc]),
                        fmaxf(pool[2][pr][oc], pool[3][pr][oc]));
        v += bias[oc];
        float s0 = slope[0];
        v = (v >= 0.f) ? v : s0 * v;
        int py = pyg * 3 + pyl;
        int o = (((n * 11 + pz + 1) * 11 + py + 1) * 12 + px + 1) * 32 + oc;
        ushort h = f2h(v);
        P2h[o] = h;
        P2l[o] = f2h(v - h2f(h));
    }
}

// ---- conv2 MFMA: P2h/P2l [80][11][11][12][32] -> pool -> P3 fp32 [n][64][64]
__global__ __launch_bounds__(256)
void conv2_mfma(const ushort* __restrict__ P2h, const ushort* __restrict__ P2l,
                const ushort* __restrict__ Bph, const ushort* __restrict__ Bpl,
                const int* __restrict__ Dt,
                const float* __restrict__ bias, const float* __restrict__ slope,
                float* __restrict__ P3)
{
    const int n  = blockIdx.x >> 2, zq = blockIdx.x & 3;
    const int tid = threadIdx.x, lane = tid & 63, w = tid >> 6;
    const int q = lane >> 4, l15 = lane & 15;

    __shared__ float pool[2][2][4][4][64];    // [my][ozl][py][px][oc] 16 KB

    const int ozl = w >> 1, oyp0 = 2 * (w & 1);
    const int oz  = zq * 2 + ozl;
    const int myA = l15 >> 3, mxA = l15 & 7;

    int ab[2];
    ab[0] = (((n * 11 + oz) * 11 + oyp0 * 2 + myA) * 12 + mxA) * 32 + q * 8;
    ab[1] = ab[0] + 2 * 12 * 32;

    f32x4 acc[2][4] = {};
    const f16x8* BH = (const f16x8*)Bph;
    const f16x8* BL = (const f16x8*)Bpl;

    f16x8 ahv[2][2], alv[2][2], bhv[2][4], blv[2][4];

    auto LOADS = [&](int s, int j) {
        int d = Dt[s];
        #pragma unroll
        for (int t = 0; t < 2; ++t) {
            ahv[j][t] = *(const f16x8u*)(P2h + ab[t] + d);
            alv[j][t] = *(const f16x8u*)(P2l + ab[t] + d);
        }
        #pragma unroll
        for (int nt = 0; nt < 4; ++nt) {
            bhv[j][nt] = BH[(s * 4 + nt) * 64 + lane];
            blv[j][nt] = BL[(s * 4 + nt) * 64 + lane];
        }
    };
    auto COMP = [&](int j) {
        #pragma unroll
        for (int t = 0; t < 2; ++t)
            #pragma unroll
            for (int nt = 0; nt < 4; ++nt) {
                acc[t][nt] = MFMA16(ahv[j][t], bhv[j][nt], acc[t][nt]);
                acc[t][nt] = MFMA16(alv[j][t], bhv[j][nt], acc[t][nt]);
                acc[t][nt] = MFMA16(ahv[j][t], blv[j][nt], acc[t][nt]);
            }
    };

    LOADS(0, 0); LOADS(1, 1);
    for (int s = 0; s < 62; s += 2) {
        COMP(0); LOADS(s + 2, 0);
        COMP(1); LOADS(s + 3, 1);
    }
    COMP(0); COMP(1);

    const int myD = q >> 1, pxe = (q & 1) * 2;
    #pragma unroll
    for (int t = 0; t < 2; ++t) {
        int py = oyp0 + t;
        #pragma unroll
        for (int nt = 0; nt < 4; ++nt) {
            int oc = nt * 16 + l15;
            pool[myD][ozl][py][pxe][oc]     = fmaxf(acc[t][nt][0], acc[t][nt][1]);
            pool[myD][ozl][py][pxe + 1][oc] = fmaxf(acc[t][nt][2], acc[t][nt][3]);
        }
    }
    __syncthreads();

    for (int t2 = tid; t2 < 1024; t2 += 256) {
        int oc = t2 & 63, r = t2 >> 6;
        int py = r >> 2, px = r & 3;
        float v = fmaxf(fmaxf(pool[0][0][py][px][oc], pool[0][1][py][px][oc]),
                        fmaxf(pool[1][0][py][px][oc], pool[1][1][py][px][oc]));
        v += bias[oc];
        float a = slope[0];
        v = (v >= 0.f) ? v : a * v;
        P3[((long)n * 64 + oc) * 64 + zq * 16 + py * 4 + px] = v;
    }
}

// ---- conv3 (fp32 direct) ----
__global__ void conv3_kernel(const float* __restrict__ in,
                             const float* __restrict__ w,
                             const float* __restrict__ bias,
                             const float* __restrict__ slope,
                             float* __restrict__ out)
{
    int idx = blockIdx.x * blockDim.x + threadIdx.x;
    const int TOTAL = 80 * 64 * 8;
    if (idx >= TOTAL) return;
    int p  = idx & 7;
    int oc = (idx >> 3) & 63;
    int n  = idx >> 9;
    int ox = p & 1, oy = (p >> 1) & 1, oz = p >> 2;

    const float* inb = in + (long)n * 64 * 64;
    const float* wb  = w + (long)oc * 64 * 27;

    float acc = 0.f;
    for (int ic = 0; ic < 64; ++ic) {
        const float* inc = inb + ic * 64;
        const float* wc  = wb + ic * 27;
        #pragma unroll
        for (int kz = 0; kz < 3; ++kz)
            #pragma unroll
            for (int ky = 0; ky < 3; ++ky)
                #pragma unroll
                for (int kx = 0; kx < 3; ++kx)
                    acc += wc[(kz * 3 + ky) * 3 + kx] *
                           inc[((oz + kz) * 4 + (oy + ky)) * 4 + (ox + kx)];
    }
    float v = acc + bias[oc];
    float a = slope[0];
    v = (v >= 0.f) ? v : a * v;
    out[idx] = v;
}

// ---- comm-FC ----
template<int D, int O, bool PRELU_ON>
__global__ void comm_fc_kernel(const float* __restrict__ feat,
                               const float* __restrict__ w,
                               const float* __restrict__ bias,
                               const float* __restrict__ slope,
                               float* __restrict__ out)
{
    const int a = blockIdx.x;
    const int b = blockIdx.y;

    __shared__ __align__(16) float cat[2 * D];
    for (int i = threadIdx.x; i < D; i += blockDim.x) {
        float m = 0.f;
        #pragma unroll
        for (int aa = 0; aa < 5; ++aa) m += feat[(b * 5 + aa) * D + i];
        cat[i]     = feat[(b * 5 + a) * D + i];
        cat[D + i] = m * 0.2f;
    }
    __syncthreads();

    for (int o = threadIdx.x; o < O; o += blockDim.x) {
        const float4* wr = (const float4*)(w + ((long)(a * O) + o) * 2 * D);
        const float4* cr = (const float4*)cat;
        float acc = 0.f;
        for (int i = 0; i < 2 * D / 4; ++i) {
            float4 wv = wr[i];
            float4 cv = cr[i];
            acc += wv.x * cv.x + wv.y * cv.y + wv.z * cv.z + wv.w * cv.w;
        }
        acc += bias[a * O + o];
        if constexpr (PRELU_ON) {
            float s = slope[0];
            acc = (acc >= 0.f) ? acc : s * acc;
        }
        out[(b * 5 + a) * O + o] = acc;
    }
}

extern "C" void kernel_launch(void* const* d_in, const int* in_sizes, int n_in,
                              void* d_out, int out_size, void* d_ws, size_t ws_size,
                              hipStream_t stream)
{
    const float* x    = (const float*)d_in[0];
    const float* c0w  = (const float*)d_in[1];
    const float* c0b  = (const float*)d_in[2];
    const float* p0   = (const float*)d_in[3];
    const float* c1w  = (const float*)d_in[4];
    const float* c1b  = (const float*)d_in[5];
    const float* p1   = (const float*)d_in[6];
    const float* c2w  = (const float*)d_in[7];
    const float* c2b  = (const float*)d_in[8];
    const float* p2   = (const float*)d_in[9];
    const float* c3w  = (const float*)d_in[10];
    const float* c3b  = (const float*)d_in[11];
    const float* p3   = (const float*)d_in[12];
    const float* f1w  = (const float*)d_in[13];
    const float* f1b  = (const float*)d_in[14];
    const float* p4   = (const float*)d_in[15];
    const float* f2w  = (const float*)d_in[16];
    const float* f2b  = (const float*)d_in[17];
    const float* p5   = (const float*)d_in[18];
    const float* f3w  = (const float*)d_in[19];
    const float* f3b  = (const float*)d_in[20];

    char* ws = (char*)d_ws;
    ushort* hi0  = (ushort*)(ws);                         // 33,930,240 el f16
    ushort* hi1  = (ushort*)(ws + 67860480);              // 32,501,760 el f16
    ushort* P2h  = (ushort*)(ws + 132864000);             //  3,717,120 el f16
    ushort* P2l  = (ushort*)(ws + 140298240);             //  3,717,120 el f16
    float*  P3   = (float*) (ws + 147732480);             //    327,680 el
    float*  feat0= (float*) (ws + 149043200);
    float*  feat1= (float*) (ws + 149207040);
    float*  feat2= (float*) (ws + 149288960);
    ushort* Bp0  = (ushort*)(ws + 149329920);             // 19,456 el
    ushort* Bp1  = (ushort*)(ws + 149368832);             // 129,024 el
    int2*   Dtx0 = (int2*)  (ws + 149626880);             // 19*64 int2 = 9728 B
    ushort* Bp2h = (ushort*)(ws + 149700000);             // 131,072 el
    ushort* Bp2l = (ushort*)(ws + 149962144);             // 131,072 el
    int*    Dt2  = (int*)   (ws + 150224288);             // 64

    // zero halos of hi1 + all of P2h/P2l (hi0 halos written by pad_input now)
    hipMemsetAsync(ws + 67860480, 0, 79872000, stream);

    pack_w0<<<76, 256, 0, stream>>>(c0w, Bp0, Dtx0);
    pack_w1<<<504, 256, 0, stream>>>(c1w, Bp1);
    pack_w2<<<512, 256, 0, stream>>>(c2w, Bp2h, Bp2l, Dt2);
    pad_input_kernel<<<(80 * 47 * 47 * 48 + 255) / 256, 256, 0, stream>>>(x, hi0);

    conv0_mfma<<<dim3(231, 1, 80), 256, 0, stream>>>(hi0, Bp0, Dtx0,
                                                     c0b, p0, hi1);
    conv1_mfma<<<dim3(27, 1, 80), 256, 0, stream>>>(hi1, Bp1,
                                                    c1b, p1, P2h, P2l);
    conv2_mfma<<<dim3(320), 256, 0, stream>>>(P2h, P2l, Bp2h, Bp2l, Dt2,
                                              c2b, p2, P3);

    conv3_kernel<<<dim3(160), dim3(256), 0, stream>>>(P3, c3w, c3b, p3, feat0);

    comm_fc_kernel<512, 256, true>
        <<<dim3(5, 16), dim3(256), 0, stream>>>(feat0, f1w, f1b, p4, feat1);
    comm_fc_kernel<256, 128, true>
        <<<dim3(5, 16), dim3(256), 0, stream>>>(feat1, f2w, f2b, p5, feat2);
    comm_fc_kernel<128, 6, false>
        <<<dim3(5, 16), dim3(64), 0, stream>>>(feat2, f3w, f3b, nullptr, (float*)d_out);
}

// Round 9
// 857.869 us; speedup vs baseline: 1.2965x; 1.2965x over previous
//
#include <hip/hip_runtime.h>

// ---------------------------------------------------------------------------
// CommNet round 16: revert conv0 to R14 (309us) + conv2 N-split + pack fusion.
//  R15 post-mortem: per-lane delta table Dtx[s*64+lane] = VMEM load on the
//  address critical path -> every step serialized on ~200cy table latency
//  (309->565us, VGPR 68->100, occ 33->23). Wave-uniform tables (int4 Dt[s],
//  s_load + cndmask) are the right pattern -> exact R14 conv0 restored.
//  conv2: 320 blocks = 1.25/CU (half the GPU does a 2nd serial pass); split
//  N into 2 blocks of 32 oc -> 640 blocks (2.5/CU), 12 MFMA/step/wave.
//  pack_w0/w1/w2 fused into one launch.
// Layouts (HW-verified): A[m=lane&15][k=q*8+j], B[n=lane&15][k=q*8+j],
//  D col=lane&15, row=q*4+reg.
// ---------------------------------------------------------------------------

typedef __attribute__((ext_vector_type(8)))  _Float16 f16x8;
typedef __attribute__((ext_vector_type(8), aligned(8))) _Float16 f16x8u; // 8B-aligned 16B access
typedef __attribute__((ext_vector_type(4)))  float f32x4;

__device__ __forceinline__ ushort f2h(float f) {
    union { _Float16 h; ushort u; } v;
    v.h = (_Float16)f;                       // v_cvt_f16_f32, RNE
    return v.u;
}
__device__ __forceinline__ float h2f(ushort h) {
    union { ushort u; _Float16 h; } v; v.u = h;
    return (float)v.h;
}

#define MFMA16(A, B, C) __builtin_amdgcn_mfma_f32_16x16x32_f16(A, B, C, 0, 0, 0)

// ---- prep: x [80][4][45^3] fp32 -> hi0 NDHWC padded [80][47][47][48][4] f16
// Covers the FULL padded volume (halos written as zeros -> no memset).
__global__ void pad_input_kernel(const float* __restrict__ x,
                                 ushort* __restrict__ hi)
{
    int t = blockIdx.x * 256 + threadIdx.x;
    const int TOT = 80 * 47 * 47 * 48;
    if (t >= TOT) return;
    int xo = t % 48, r = t / 48;
    int yo = r % 47; r /= 47;
    int zo = r % 47; int n = r / 47;
    ushort h4[4] = {0, 0, 0, 0};
    if (zo >= 1 && zo <= 45 && yo >= 1 && yo <= 45 && xo >= 1 && xo <= 45) {
        int ib = n * 4 * 91125 + (zo - 1) * 2025 + (yo - 1) * 45 + (xo - 1);
        #pragma unroll
        for (int ic = 0; ic < 4; ++ic)
            h4[ic] = f2h(x[ib + ic * 91125] * (1.f / 255.f));
    }
    *(ushort4*)(hi + t * 4) = *(ushort4*)h4;
}

// ---- fused weight pack: conv0 + conv1 + conv2 (one launch, 512 blocks)
// conv0: Bp0[19 s][2 ot][64 lane][8 j]; k=((kz*5+ky)*6+kx)*4+ic, kx==5 zero.
//        Dt0[19] int4 = per-q LDS deltas (kz*8+ky)*192+kx*4.
// conv1: Bp1[126 s][2 ot][64][8]; s = tap kz-major (125 real).
// conv2: B2h/B2l[64 s][4 nt][64 l][8 j] hi/lo; Dt2[64] global deltas.
__global__ void pack_all(const float* __restrict__ w0,
                         const float* __restrict__ w1,
                         const float* __restrict__ w2,
                         ushort* __restrict__ Bp0, int4* __restrict__ Dt0,
                         ushort* __restrict__ Bp1,
                         ushort* __restrict__ B2h, ushort* __restrict__ B2l,
                         int* __restrict__ Dt2)
{
    int t = blockIdx.x * 256 + threadIdx.x;
    if (t < 19 * 2 * 64 * 8) {
        int j = t & 7, l = (t >> 3) & 63, ot = (t >> 9) & 1, s = t >> 10;
        int oc = ot * 16 + (l & 15);
        int k = 32 * s + ((l >> 4) << 3) + j;
        float v = 0.f;
        if (k < 600) {
            int ic = k & 3, t6 = k >> 2;
            int kx = t6 % 6, q = t6 / 6, ky = q % 5, kz = q / 5;
            if (kx < 5) v = w0[(oc * 4 + ic) * 125 + kz * 25 + ky * 5 + kx];
        }
        Bp0[t] = f2h(v);
    }
    if (t < 19) {
        int dd[4];
        #pragma unroll
        for (int q = 0; q < 4; ++q) {
            int k = 32 * t + 8 * q;
            if (k < 600) {
                int t6 = k >> 2;
                int kx = t6 % 6, qq = t6 / 6;
                dd[q] = ((qq / 5) * 8 + (qq % 5)) * 192 + kx * 4;    // LDS els
            } else dd[q] = 0;
        }
        int4 d; d.x = dd[0]; d.y = dd[1]; d.z = dd[2]; d.w = dd[3];
        Dt0[t] = d;
    }
    if (t < 126 * 2 * 64 * 8) {
        int j = t & 7, l = (t >> 3) & 63, ot = (t >> 9) & 1, s = t >> 10;
        int oc = ot * 16 + (l & 15);
        int ic = ((l >> 4) << 3) + j;
        Bp1[t] = (s < 125) ? f2h(w1[(oc * 32 + ic) * 125 + s]) : (ushort)0;
    }
    if (t < 64 * 4 * 64 * 8) {
        int j = t & 7, l = (t >> 3) & 63, nt = (t >> 9) & 3, s = t >> 11;
        int oc = nt * 16 + (l & 15);
        int ic = ((l >> 4) << 3) + j;
        int kz = s >> 4, ky = (s >> 2) & 3, kx = s & 3;
        float v = w2[(oc * 32 + ic) * 64 + kz * 16 + ky * 4 + kx];
        ushort h = f2h(v);
        B2h[t] = h;
        B2l[t] = f2h(v - h2f(h));
    }
    if (t < 64) {
        int kz = t >> 4, ky = (t >> 2) & 3, kx = t & 3;
        Dt2[t] = ((kz * 11 + ky) * 12 + kx) * 32;                    // x-unit=32
    }
}

// ---- conv0 MFMA: hi0 [80][47][47][48][4] f16 -> hi1 [80][23][23][24][32] f16
// R14-exact: block=(pz,pyg); waves (dz,pyl); dy-merged; A staged in LDS
// As[6z][8y][192] (18KB); per step 6 ds_reads + 2 B globals; int4 scalar Dt.
__global__ __launch_bounds__(256)
void conv0_mfma(const ushort* __restrict__ hi0,
                const ushort* __restrict__ Bp, const int4* __restrict__ DtL,
                const float* __restrict__ bias, const float* __restrict__ slope,
                ushort* __restrict__ hi1)
{
    const int n   = blockIdx.z;
    const int pz  = blockIdx.x / 11, pyg = blockIdx.x % 11;
    const int tid = threadIdx.x, lane = tid & 63, w = tid >> 6;
    const int dz  = w >> 1, pyl = w & 1;
    const int l15 = lane & 15, q = lane >> 4;

    __shared__ float pool[2][2][21][32];                 // 10.75 KB
    __shared__ __align__(16) ushort As[6 * 8 * 192];     // 18 KB

    {   // stage A footprint: z [2pz,2pz+6), y [4pyg,4pyg+8), x [0,48)*4ic
        const int base = ((n * 47 + 2 * pz) * 47 + 4 * pyg) * 192;
        for (int u = tid; u < 2304; u += 256) {          // 8B units (4 els)
            int zr = u / 384, rem = u - zr * 384;        // rem = yr*48 + xu
            int src = base + zr * 9024 + rem * 4;        // (zr*47+yr)*192+xu*4
            *(uint2*)(As + u * 4) = *(const uint2*)(hi0 + src);
        }
    }

    const float sl = slope[0];
    int lb[3];
    #pragma unroll
    for (int xt = 0; xt < 3; ++xt) {
        int x = xt * 16 + l15;
        int xr = x > 41 ? 41 : x;
        lb[xt] = (dz * 8 + 2 * pyl) * 192 + xr * 4;
    }

    f32x4 acc[2][3][2] = {};                  // [dy][xt][ot]
    const f16x8* Bv = (const f16x8*)Bp;
    f16x8 avd[2][3][2], b0v[2], b1v[2];       // [j][xt][dy]

    auto LOADS = [&](int s, int j) {
        int4 dd = DtL[s];
        int delta = q == 0 ? dd.x : q == 1 ? dd.y : q == 2 ? dd.z : dd.w;
        b0v[j] = Bv[(2 * s) * 64 + lane];
        b1v[j] = Bv[(2 * s + 1) * 64 + lane];
        #pragma unroll
        for (int xt = 0; xt < 3; ++xt) {
            const ushort* p = As + lb[xt] + delta;
            avd[j][xt][0] = *(const f16x8u*)p;
            avd[j][xt][1] = *(const f16x8u*)(p + 192);   // dy=1: +1 y-row
        }
    };
    auto COMP = [&](int j) {
        #pragma unroll
        for (int xt = 0; xt < 3; ++xt)
            #pragma unroll
            for (int dy = 0; dy < 2; ++dy) {
                acc[dy][xt][0] = MFMA16(avd[j][xt][dy], b0v[j], acc[dy][xt][0]);
                acc[dy][xt][1] = MFMA16(avd[j][xt][dy], b1v[j], acc[dy][xt][1]);
            }
    };

    __syncthreads();                          // A staged

    LOADS(0, 0); LOADS(1, 1);
    for (int s = 0; s < 16; s += 2) {         // branch-free body
        COMP(0); LOADS(s + 2, 0);
        COMP(1); LOADS(s + 3, 1);             // max s+3 = 17
    }
    COMP(0); LOADS(18, 0);
    COMP(1);
    COMP(0);

    #pragma unroll
    for (int xt = 0; xt < 3; ++xt)
        #pragma unroll
        for (int ot = 0; ot < 2; ++ot) {
            float m0 = fmaxf(acc[0][xt][ot][0], acc[1][xt][ot][0]);
            float m1 = fmaxf(acc[0][xt][ot][1], acc[1][xt][ot][1]);
            float m2 = fmaxf(acc[0][xt][ot][2], acc[1][xt][ot][2]);
            float m3 = fmaxf(acc[0][xt][ot][3], acc[1][xt][ot][3]);
            int pxe = xt * 8 + 2 * q, pxo = pxe + 1;
            if (pxe < 21) pool[dz][pyl][pxe][ot * 16 + l15] = fmaxf(m0, m1);
            if (pxo < 21) pool[dz][pyl][pxo][ot * 16 + l15] = fmaxf(m2, m3);
        }
    __syncthreads();

    for (int t2 = tid; t2 < 1344; t2 += 256) {
        int oc = t2 & 31, r = t2 >> 5;
        int px = r % 21, pyl2 = r / 21;
        int py2 = 2 * pyg + pyl2;
        if (py2 > 20) continue;
        float v = fmaxf(pool[0][pyl2][px][oc], pool[1][pyl2][px][oc]);
        v += bias[oc];
        v = (v >= 0.f) ? v : sl * v;
        int o = (((n * 23 + pz + 1) * 23 + py2 + 1) * 24 + px + 1) * 32 + oc;
        hi1[o] = f2h(v);
    }
}

// ---- conv1 MFMA: hi1 [80][23][23][24][32] f16 -> P2h/P2l f16 NDHWC padded
// A via LDS ring of 3 z-slices (15.4KB each), phased over kz (5 x 25 steps),
// T14 async stage. B from global. M flat = pyl*18+x (4 tiles of 16).
__global__ __launch_bounds__(256)
void conv1_mfma(const ushort* __restrict__ hi1,
                const ushort* __restrict__ Bp,
                const float* __restrict__ bias, const float* __restrict__ slope,
                ushort* __restrict__ P2h, ushort* __restrict__ P2l)
{
    const int n   = blockIdx.z;
    const int pz  = blockIdx.x / 3, pyg = blockIdx.x % 3;
    const int tid = threadIdx.x, lane = tid & 63, w = tid >> 6;
    const int dz = w >> 1, dy = w & 1;
    const int q = lane >> 4, l15 = lane & 15;

    __shared__ float pool[4][27][32];                    // 13.5 KB
    __shared__ __align__(16) ushort As[3 * 7680];        // 45 KB (3 z-slices)

    int lb[4];
    #pragma unroll
    for (int t = 0; t < 4; ++t) {
        int flat = t * 16 + l15;
        if (flat > 53) flat = 53;
        int pyl = flat / 18, x = flat - pyl * 18;
        lb[t] = (2 * pyl + dy) * 768 + x * 32 + q * 8;
    }

    f16x8 stg[4];
    auto STAGE_LOAD = [&](int zoff) {                    // issue early (T14)
        const ushort* src = hi1 + ((n * 23 + 2 * pz + zoff) * 23 + 6 * pyg) * 768;
        #pragma unroll
        for (int r = 0; r < 4; ++r) {
            int u = tid + r * 256;
            if (u < 960) stg[r] = *(const f16x8*)(src + u * 8);
        }
    };
    auto STAGE_WRITE = [&](int zoff) {                   // write late
        int slot = zoff % 3;
        #pragma unroll
        for (int r = 0; r < 4; ++r) {
            int u = tid + r * 256;
            if (u < 960) *(f16x8*)(As + slot * 7680 + u * 8) = stg[r];
        }
    };

    f32x4 acc[4][2] = {};
    const f16x8* Bv = (const f16x8*)Bp;
    f16x8 ahv[2][4], b0v[2], b1v[2];

    // prologue: slices 0,1
    STAGE_LOAD(0); STAGE_WRITE(0);
    STAGE_LOAD(1); STAGE_WRITE(1);
    __syncthreads();

    for (int kz = 0; kz < 5; ++kz) {
        if (kz < 4) STAGE_LOAD(kz + 2);
        const int slotbase = ((dz + kz) % 3) * 7680;
        const int sg0 = kz * 25;

        auto LOADS = [&](int s, int j) {                 // s in [0,25)
            int delta = (s / 5) * 768 + (s % 5) * 32;
            int sg = sg0 + s;
            b0v[j] = Bv[(2 * sg) * 64 + lane];
            b1v[j] = Bv[(2 * sg + 1) * 64 + lane];
            #pragma unroll
            for (int t = 0; t < 4; ++t)
                ahv[j][t] = *(const f16x8u*)(As + slotbase + lb[t] + delta);
        };
        auto COMP = [&](int j) {
            #pragma unroll
            for (int t = 0; t < 4; ++t) {
                acc[t][0] = MFMA16(ahv[j][t], b0v[j], acc[t][0]);
                acc[t][1] = MFMA16(ahv[j][t], b1v[j], acc[t][1]);
            }
        };

        LOADS(0, 0); LOADS(1, 1);
        for (int s = 0; s < 24; s += 2) {
            COMP(0); LOADS(s + 2 > 24 ? 24 : s + 2, 0);
            COMP(1); LOADS(s + 3 > 24 ? 24 : s + 3, 1);
        }
        COMP(0);                                         // step 24

        __syncthreads();                                 // phase reads done
        if (kz < 4) STAGE_WRITE(kz + 2);
        __syncthreads();                                 // writes visible
    }

    #pragma unroll
    for (int t = 0; t < 4; ++t) {
        int p0 = t * 8 + q * 2;
        float e0 = fmaxf(acc[t][0][0], acc[t][0][1]);
        float o0 = fmaxf(acc[t][0][2], acc[t][0][3]);
        float e1 = fmaxf(acc[t][1][0], acc[t][1][1]);
        float o1 = fmaxf(acc[t][1][2], acc[t][1][3]);
        if (p0 < 27)     { pool[w][p0][l15] = e0;     pool[w][p0][16 + l15] = e1; }
        if (p0 + 1 < 27) { pool[w][p0 + 1][l15] = o0; pool[w][p0 + 1][16 + l15] = o1; }
    }
    __syncthreads();

    for (int t2 = tid; t2 < 864; t2 += 256) {
        int oc = t2 & 31, pr = t2 >> 5;          // pr = pyl*9 + px
        int pyl = pr / 9, px = pr % 9;
        float v = fmaxf(fmaxf(pool[0][pr][oc], pool[1][pr][oc]),
                        fmaxf(pool[2][pr][oc], pool[3][pr][oc]));
        v += bias[oc];
        float s0 = slope[0];
        v = (v >= 0.f) ? v : s0 * v;
        int py = pyg * 3 + pyl;
        int o = (((n * 11 + pz + 1) * 11 + py + 1) * 12 + px + 1) * 32 + oc;
        ushort h = f2h(v);
        P2h[o] = h;
        P2l[o] = f2h(v - h2f(h));
    }
}

// ---- conv2 MFMA (R16 N-split): P2h/P2l [80][11][11][12][32] -> P3 [n][64][64]
// block = (n, zq, og): og selects 32 of 64 oc -> 640 blocks (2.5/CU, was 1.25).
// Per wave-step: 2 ti x 2 nt x 3-term hi/lo = 12 MFMA.
__global__ __launch_bounds__(256)
void conv2_mfma(const ushort* __restrict__ P2h, const ushort* __restrict__ P2l,
                const ushort* __restrict__ Bph, const ushort* __restrict__ Bpl,
                const int* __restrict__ Dt,
                const float* __restrict__ bias, const float* __restrict__ slope,
                float* __restrict__ P3)
{
    const int n  = blockIdx.x >> 3, zq = (blockIdx.x >> 1) & 3, og = blockIdx.x & 1;
    const int tid = threadIdx.x, lane = tid & 63, w = tid >> 6;
    const int q = lane >> 4, l15 = lane & 15;

    __shared__ float pool[2][2][4][4][32];    // [my][ozl][py][px][ocl] 8 KB

    const int ozl = w >> 1, oyp0 = 2 * (w & 1);
    const int oz  = zq * 2 + ozl;
    const int myA = l15 >> 3, mxA = l15 & 7;

    int ab[2];
    ab[0] = (((n * 11 + oz) * 11 + oyp0 * 2 + myA) * 12 + mxA) * 32 + q * 8;
    ab[1] = ab[0] + 2 * 12 * 32;

    f32x4 acc[2][2] = {};                     // [ti][nt]
    const f16x8* BH = (const f16x8*)Bph;
    const f16x8* BL = (const f16x8*)Bpl;

    f16x8 ahv[2][2], alv[2][2], bhv[2][2], blv[2][2];

    auto LOADS = [&](int s, int j) {
        int d = Dt[s];
        #pragma unroll
        for (int t = 0; t < 2; ++t) {
            ahv[j][t] = *(const f16x8u*)(P2h + ab[t] + d);
            alv[j][t] = *(const f16x8u*)(P2l + ab[t] + d);
        }
        #pragma unroll
        for (int nt = 0; nt < 2; ++nt) {
            bhv[j][nt] = BH[(s * 4 + og * 2 + nt) * 64 + lane];
            blv[j][nt] = BL[(s * 4 + og * 2 + nt) * 64 + lane];
        }
    };
    auto COMP = [&](int j) {
        #pragma unroll
        for (int t = 0; t < 2; ++t)
            #pragma unroll
            for (int nt = 0; nt < 2; ++nt) {
                acc[t][nt] = MFMA16(ahv[j][t], bhv[j][nt], acc[t][nt]);
                acc[t][nt] = MFMA16(alv[j][t], bhv[j][nt], acc[t][nt]);
                acc[t][nt] = MFMA16(ahv[j][t], blv[j][nt], acc[t][nt]);
            }
    };

    LOADS(0, 0); LOADS(1, 1);
    for (int s = 0; s < 62; s += 2) {
        COMP(0); LOADS(s + 2, 0);
        COMP(1); LOADS(s + 3, 1);
    }
    COMP(0); COMP(1);

    const int myD = q >> 1, pxe = (q & 1) * 2;
    #pragma unroll
    for (int t = 0; t < 2; ++t) {
        int py = oyp0 + t;
        #pragma unroll
        for (int nt = 0; nt < 2; ++nt) {
            int ocl = nt * 16 + l15;
            pool[myD][ozl][py][pxe][ocl]     = fmaxf(acc[t][nt][0], acc[t][nt][1]);
            pool[myD][ozl][py][pxe + 1][ocl] = fmaxf(acc[t][nt][2], acc[t][nt][3]);
        }
    }
    __syncthreads();

    for (int t2 = tid; t2 < 512; t2 += 256) {
        int ocl = t2 & 31, r = t2 >> 5;
        int py = r >> 2, px = r & 3;
        float v = fmaxf(fmaxf(pool[0][0][py][px][ocl], pool[0][1][py][px][ocl]),
                        fmaxf(pool[1][0][py][px][ocl], pool[1][1][py][px][ocl]));
        int oc = og * 32 + ocl;
        v += bias[oc];
        float a = slope[0];
        v = (v >= 0.f) ? v : a * v;
        P3[((long)n * 64 + oc) * 64 + zq * 16 + py * 4 + px] = v;
    }
}

// ---- conv3 (fp32 direct) ----
__global__ void conv3_kernel(const float* __restrict__ in,
                             const float* __restrict__ w,
                             const float* __restrict__ bias,
                             const float* __restrict__ slope,
                             float* __restrict__ out)
{
    int idx = blockIdx.x * blockDim.x + threadIdx.x;
    const int TOTAL = 80 * 64 * 8;
    if (idx >= TOTAL) return;
    int p  = idx & 7;
    int oc = (idx >> 3) & 63;
    int n  = idx >> 9;
    int ox = p & 1, oy = (p >> 1) & 1, oz = p >> 2;

    const float* inb = in + (long)n * 64 * 64;
    const float* wb  = w + (long)oc * 64 * 27;

    float acc = 0.f;
    for (int ic = 0; ic < 64; ++ic) {
        const float* inc = inb + ic * 64;
        const float* wc  = wb + ic * 27;
        #pragma unroll
        for (int kz = 0; kz < 3; ++kz)
            #pragma unroll
            for (int ky = 0; ky < 3; ++ky)
                #pragma unroll
                for (int kx = 0; kx < 3; ++kx)
                    acc += wc[(kz * 3 + ky) * 3 + kx] *
                           inc[((oz + kz) * 4 + (oy + ky)) * 4 + (ox + kx)];
    }
    float v = acc + bias[oc];
    float a = slope[0];
    v = (v >= 0.f) ? v : a * v;
    out[idx] = v;
}

// ---- comm-FC ----
template<int D, int O, bool PRELU_ON>
__global__ void comm_fc_kernel(const float* __restrict__ feat,
                               const float* __restrict__ w,
                               const float* __restrict__ bias,
                               const float* __restrict__ slope,
                               float* __restrict__ out)
{
    const int a = blockIdx.x;
    const int b = blockIdx.y;

    __shared__ __align__(16) float cat[2 * D];
    for (int i = threadIdx.x; i < D; i += blockDim.x) {
        float m = 0.f;
        #pragma unroll
        for (int aa = 0; aa < 5; ++aa) m += feat[(b * 5 + aa) * D + i];
        cat[i]     = feat[(b * 5 + a) * D + i];
        cat[D + i] = m * 0.2f;
    }
    __syncthreads();

    for (int o = threadIdx.x; o < O; o += blockDim.x) {
        const float4* wr = (const float4*)(w + ((long)(a * O) + o) * 2 * D);
        const float4* cr = (const float4*)cat;
        float acc = 0.f;
        for (int i = 0; i < 2 * D / 4; ++i) {
            float4 wv = wr[i];
            float4 cv = cr[i];
            acc += wv.x * cv.x + wv.y * cv.y + wv.z * cv.z + wv.w * cv.w;
        }
        acc += bias[a * O + o];
        if constexpr (PRELU_ON) {
            float s = slope[0];
            acc = (acc >= 0.f) ? acc : s * acc;
        }
        out[(b * 5 + a) * O + o] = acc;
    }
}

extern "C" void kernel_launch(void* const* d_in, const int* in_sizes, int n_in,
                              void* d_out, int out_size, void* d_ws, size_t ws_size,
                              hipStream_t stream)
{
    const float* x    = (const float*)d_in[0];
    const float* c0w  = (const float*)d_in[1];
    const float* c0b  = (const float*)d_in[2];
    const float* p0   = (const float*)d_in[3];
    const float* c1w  = (const float*)d_in[4];
    const float* c1b  = (const float*)d_in[5];
    const float* p1   = (const float*)d_in[6];
    const float* c2w  = (const float*)d_in[7];
    const float* c2b  = (const float*)d_in[8];
    const float* p2   = (const float*)d_in[9];
    const float* c3w  = (const float*)d_in[10];
    const float* c3b  = (const float*)d_in[11];
    const float* p3   = (const float*)d_in[12];
    const float* f1w  = (const float*)d_in[13];
    const float* f1b  = (const float*)d_in[14];
    const float* p4   = (const float*)d_in[15];
    const float* f2w  = (const float*)d_in[16];
    const float* f2b  = (const float*)d_in[17];
    const float* p5   = (const float*)d_in[18];
    const float* f3w  = (const float*)d_in[19];
    const float* f3b  = (const float*)d_in[20];

    char* ws = (char*)d_ws;
    ushort* hi0  = (ushort*)(ws);                         // 33,930,240 el f16
    ushort* hi1  = (ushort*)(ws + 67860480);              // 32,501,760 el f16
    ushort* P2h  = (ushort*)(ws + 132864000);             //  3,717,120 el f16
    ushort* P2l  = (ushort*)(ws + 140298240);             //  3,717,120 el f16
    float*  P3   = (float*) (ws + 147732480);             //    327,680 el
    float*  feat0= (float*) (ws + 149043200);
    float*  feat1= (float*) (ws + 149207040);
    float*  feat2= (float*) (ws + 149288960);
    ushort* Bp0  = (ushort*)(ws + 149329920);             // 19,456 el
    ushort* Bp1  = (ushort*)(ws + 149368832);             // 129,024 el
    int4*   Dt0  = (int4*)  (ws + 149626880);             // 19 (LDS deltas)
    ushort* Bp2h = (ushort*)(ws + 149700000);             // 131,072 el
    ushort* Bp2l = (ushort*)(ws + 149962144);             // 131,072 el
    int*    Dt2  = (int*)   (ws + 150224288);             // 64

    // zero halos of hi1 + all of P2h/P2l (hi0 halos written by pad_input)
    hipMemsetAsync(ws + 67860480, 0, 79872000, stream);

    pack_all<<<512, 256, 0, stream>>>(c0w, c1w, c2w, Bp0, Dt0, Bp1,
                                      Bp2h, Bp2l, Dt2);
    pad_input_kernel<<<(80 * 47 * 47 * 48 + 255) / 256, 256, 0, stream>>>(x, hi0);

    conv0_mfma<<<dim3(231, 1, 80), 256, 0, stream>>>(hi0, Bp0, Dt0,
                                                     c0b, p0, hi1);
    conv1_mfma<<<dim3(27, 1, 80), 256, 0, stream>>>(hi1, Bp1,
                                                    c1b, p1, P2h, P2l);
    conv2_mfma<<<dim3(640), 256, 0, stream>>>(P2h, P2l, Bp2h, Bp2l, Dt2,
                                              c2b, p2, P3);

    conv3_kernel<<<dim3(160), dim3(256), 0, stream>>>(P3, c3w, c3b, p3, feat0);

    comm_fc_kernel<512, 256, true>
        <<<dim3(5, 16), dim3(256), 0, stream>>>(feat0, f1w, f1b, p4, feat1);
    comm_fc_kernel<256, 128, true>
        <<<dim3(5, 16), dim3(256), 0, stream>>>(feat1, f2w, f2b, p5, feat2);
    comm_fc_kernel<128, 6, false>
        <<<dim3(5, 16), dim3(64), 0, stream>>>(feat2, f3w, f3b, nullptr, (float*)d_out);
}